// Round 6
// baseline (158.904 us; speedup 1.0000x reference)
//
#include <hip/hip_runtime.h>
#include <math.h>

#pragma clang fp contract(off)

#define BS 16
#define NA 8400
#define NG 128
#define NC 80
#define KTOP 13
#define QCAP 1024   // per-column in-box queue capacity (worst case ~500)

// ---- workspace layout (bytes) ----
#define OFF_BITS   0                                    // BS*NA*4 u32 = 2,150,400
#define OFF_SELCNT ((size_t)BS * NA * 16)               // BS*NA u32   =   537,600
#define OFF_FLAG   (OFF_SELCNT + (size_t)BS * NA * 4)   // 256 bytes
#define OFF_BESTK  (OFF_FLAG + 256)                     // BS*NA u64   = 1,075,200

// ---- output layout (float elements) ----
#define OUT_CLS    0
#define OUT_BBOX   (BS * NA)
#define OUT_SCORES (OUT_BBOX + BS * NA * 4)
#define OUT_MASK   (OUT_SCORES + BS * NA * NC)
#define OUT_NORM   (OUT_MASK + BS * NA)

__device__ __forceinline__ float dev_ciou(float px1, float py1, float px2, float py2,
                                          float gx1, float gy1, float gx2, float gy2) {
    const float eps = 1e-7f;
    float iw = fminf(px2, gx2) - fmaxf(px1, gx1); iw = fmaxf(iw, 0.0f);
    float ih = fminf(py2, gy2) - fmaxf(py1, gy1); ih = fmaxf(ih, 0.0f);
    float inter = iw * ih;
    float w1 = px2 - px1;
    float h1 = (py2 - py1) + eps;
    float w2 = gx2 - gx1;
    float h2 = (gy2 - gy1) + eps;
    float uni = ((w1 * h1 + w2 * h2) - inter) + eps;
    float iou = inter / uni;
    float cw = fmaxf(px2, gx2) - fminf(px1, gx1);
    float ch = fmaxf(py2, gy2) - fminf(py1, gy1);
    float c2 = (cw * cw + ch * ch) + eps;
    float tx = ((gx1 + gx2) - px1) - px2;
    float ty = ((gy1 + gy2) - py1) - py2;
    float rho2 = (tx * tx + ty * ty) / 4.0f;
    float da = atanf(w2 / h2) - atanf(w1 / h1);
    float v = ((float)(4.0 / (M_PI * M_PI))) * (da * da);
    float alpha = v / ((v - iou) + (float)(1.0 + 1e-7));
    float res = iou - (rho2 / c2 + v * alpha);
    return fmaxf(res, 0.0f);
}

// K0: zero bits/selcnt/flag, seed bestkey = pack(al=0.0f, g=0) = 127
__global__ __launch_bounds__(256) void k_init(
    unsigned int* __restrict__ bits, unsigned int* __restrict__ selcnt,
    int* __restrict__ flag, unsigned long long* __restrict__ bestkey)
{
    int i = blockIdx.x * 256 + threadIdx.x;
    if (i < BS * NA) {
        ((uint4*)bits)[i] = make_uint4(0u, 0u, 0u, 0u);
        selcnt[i] = 0u;
        bestkey[i] = 127ULL;
    }
    if (i == 0) *flag = 0;
}

// K1: fused build+select, ONE WAVE per (b,g) column — fully wave-synchronous,
// no __syncthreads, no LDS atomics. 4 independent waves per block.
// Phase 1: float4 anchor scan (2 anchors/lane), ballot-compacted LDS queue.
// Phase 2: dense align over the queue; fire-and-forget atomicMax best key.
// Phase 3: in-wave top-13 (value desc, anchor asc), batched selcnt atomics.
__global__ __launch_bounds__(256) void k_build_select(
    const float* __restrict__ scores, const float* __restrict__ pboxes,
    const float* __restrict__ anc, const int* __restrict__ glab,
    const float* __restrict__ gboxes, const float* __restrict__ gmask,
    unsigned int* __restrict__ bits, unsigned int* __restrict__ selcnt,
    int* __restrict__ flag, unsigned long long* __restrict__ bestkey)
{
    __shared__ unsigned short s_idx[4][QCAP];
    __shared__ float s_val[4][QCAP];
    int wv = threadIdx.x >> 6, lane = threadIdx.x & 63;
    int col = blockIdx.x * 4 + wv;
    int b = col >> 7, g = col & 127;
    float gm = gmask[col];                 // wave-uniform
    if (gm == 0.0f) return;                // align column exactly 0; seed covers bestkey
    float gx1 = gboxes[col * 4 + 0], gy1 = gboxes[col * 4 + 1];
    float gx2 = gboxes[col * 4 + 2], gy2 = gboxes[col * 4 + 3];
    int cls = glab[col];
    unsigned short* qi = s_idx[wv];
    float* qv = s_val[wv];
    unsigned long long lmask = (1ULL << lane) - 1ULL;

    // phase 1: ballot-compacted in-box scan, 2 anchors per lane per iteration
    int qn = 0;
    #pragma unroll 4
    for (int base = 0; base < NA / 2; base += 64) {
        int p = base + lane;
        bool h0 = false, h1 = false;
        int a0 = 2 * p, a1 = 2 * p + 1;
        if (p < NA / 2) {
            float4 ap = ((const float4*)anc)[p];
            float m0 = fminf(fminf(ap.x - gx1, ap.y - gy1), fminf(gx2 - ap.x, gy2 - ap.y));
            float m1 = fminf(fminf(ap.z - gx1, ap.w - gy1), fminf(gx2 - ap.z, gy2 - ap.w));
            h0 = (m0 > 1e-9f);
            h1 = (m1 > 1e-9f);
        }
        unsigned long long b0 = __ballot(h0);
        unsigned long long b1 = __ballot(h1);
        int c0 = __popcll(b0);
        if (h0) {
            int pos = qn + __popcll(b0 & lmask);
            if (pos < QCAP) qi[pos] = (unsigned short)a0;
        }
        if (h1) {
            int pos = qn + c0 + __popcll(b1 & lmask);
            if (pos < QCAP) qi[pos] = (unsigned short)a1;
        }
        qn += c0 + __popcll(b1);
    }
    if (qn > QCAP) qn = QCAP;

    // phase 2: dense align over the queue (queue order is irrelevant downstream)
    for (int i = lane; i < qn; i += 64) {
        int a = (int)qi[i];
        size_t t = (size_t)b * NA + a;
        float4 pb = ((const float4*)pboxes)[t];
        float iou = dev_ciou(pb.x, pb.y, pb.z, pb.w, gx1, gy1, gx2, gy2);
        float s = scores[t * NC + cls];
        float al = (s * powf(iou, 6.0f)) * gm;   // same expr as reference path
        qv[i] = (al > 1e-9f) ? al : -1.0f;       // sentinel: excluded from top-k
        // first-occurrence row argmax: al>=0 -> bits order-monotone; (127-g)
        // low bits make smaller g win ties under max. Return unused -> no wait.
        unsigned long long key =
            ((unsigned long long)__float_as_uint(al) << 32) | (unsigned int)(127 - g);
        atomicMax(&bestkey[t], key);
    }

    // phase 3: in-wave top-13; batched bits/selcnt scatter at the end
    if (!(gm > 0.0f)) return;   // column excluded from is_in (wave-uniform)
    unsigned int wins[KTOP];
    int nw = 0;
    #pragma unroll
    for (int k = 0; k < KTOP; k++) {
        float bv = -1.0f; unsigned int ba = 0xFFFFFFFFu; int bp = -1;
        for (int i = lane; i < qn; i += 64) {
            float v = qv[i]; unsigned int a = qi[i];
            if (v > bv || (v == bv && a < ba)) { bv = v; ba = a; bp = i; }
        }
        float mybv = bv; unsigned int myba = ba; int mybp = bp;
        for (int off = 1; off < 64; off <<= 1) {
            float ov = __shfl_xor(bv, off);
            unsigned int oa = (unsigned int)__shfl_xor((int)ba, off);
            if (ov > bv || (ov == bv && oa < ba)) { bv = ov; ba = oa; }
        }
        if (!(bv > 1e-9f)) break;   // rest would be filtered by align>1e-9
        wins[k] = ba; nw = k + 1;
        // exactly one lane owns ba's queue slot; its per-lane best IS (bv,ba)
        if (myba == ba && mybv == bv && mybp >= 0) qv[mybp] = -1.0f;
    }
    if (lane == 0 && nw > 0) {
        unsigned int olds[KTOP];
        #pragma unroll
        for (int k = 0; k < KTOP; k++) {
            if (k < nw) {
                size_t t = (size_t)b * NA + wins[k];
                atomicOr(&bits[t * 4 + (g >> 5)], 1u << (g & 31));   // no return
                olds[k] = atomicAdd(&selcnt[t], 1u);                 // batched waits
            }
        }
        bool c = false;
        #pragma unroll
        for (int k = 0; k < KTOP; k++) {
            if (k < nw && olds[k] >= 1u) c = true;
        }
        if (c) atomicOr(flag, 1);
    }
}

// K2: per-anchor resolution + all 5 outputs (align/iou recomputed only at set bits)
__global__ __launch_bounds__(256) void k_final(
    const float* __restrict__ scores, const float* __restrict__ pboxes,
    const int* __restrict__ glab, const float* __restrict__ gboxes,
    const float* __restrict__ gmask,
    const unsigned int* __restrict__ bits, const int* __restrict__ flagp,
    const unsigned long long* __restrict__ bestkey,
    float* __restrict__ o_cls, float* __restrict__ o_bbox, float* __restrict__ o_scores,
    float* __restrict__ o_mask, float* __restrict__ o_norm)
{
    __shared__ float4 s_gb[NG];
    __shared__ int s_gl[NG];
    __shared__ float s_gm[NG];
    int b = blockIdx.y;
    for (int i = threadIdx.x; i < NG; i += 256) {
        s_gb[i] = ((const float4*)gboxes)[b * NG + i];
        s_gl[i] = glab[b * NG + i];
        s_gm[i] = gmask[b * NG + i];
    }
    __syncthreads();
    int a = blockIdx.x * 256 + threadIdx.x;
    if (a >= NA) return;
    size_t t = (size_t)b * NA + a;
    unsigned int ew[4];
    ew[0] = bits[t * 4 + 0]; ew[1] = bits[t * 4 + 1];
    ew[2] = bits[t * 4 + 2]; ew[3] = bits[t * 4 + 3];
    int cnt = __popc(ew[0]) + __popc(ew[1]) + __popc(ew[2]) + __popc(ew[3]);
    bool conflict_any = (flagp[0] != 0);
    unsigned long long key = bestkey[t];
    float best_v = __uint_as_float((unsigned int)(key >> 32));
    int best_g = 127 - (int)(key & 0x7Fu);
    float4 pb = ((const float4*)pboxes)[t];
    const float* srow = scores + t * NC;

    bool keep = (cnt <= 1);
    float M = 0.0f, mxiou = 0.0f;
    int tgt = 0;
    float fmask = 0.0f;

    if (!conflict_any) {
        fmask = (cnt > 0) ? 1.0f : 0.0f;
        for (int w = 0; w < 4; w++) {
            if (ew[w]) { tgt = w * 32 + __ffs(ew[w]) - 1; break; }
        }
        for (int w = 0; w < 4; w++) {
            unsigned int m = ew[w];
            while (m) {
                int j = __ffs(m) - 1; m &= m - 1;
                int g = w * 32 + j;
                float4 gb = s_gb[g];
                float iv = dev_ciou(pb.x, pb.y, pb.z, pb.w, gb.x, gb.y, gb.z, gb.w);
                float s = srow[s_gl[g]];
                float av = (s * powf(iv, 6.0f)) * s_gm[g];   // bit-identical to build
                M = fmaxf(M, av);
                mxiou = fmaxf(mxiou, iv);
            }
        }
    } else if (!keep) {
        fmask = 0.0f; tgt = 0; M = 0.0f; mxiou = 0.0f;   // resolved row all zero
    } else {
        fmask = 1.0f;   // one_hot_best always contributes
        bool eff_best = ((ew[best_g >> 5] >> (best_g & 31)) & 1u) != 0u;
        int first_eff = 1 << 30;
        for (int w = 0; w < 4; w++) {
            if (ew[w]) { first_eff = w * 32 + __ffs(ew[w]) - 1; break; }
        }
        tgt = eff_best ? best_g : (first_eff < best_g ? first_eff : best_g);
        for (int w = 0; w < 4; w++) {
            unsigned int m = ew[w];
            while (m) {
                int j = __ffs(m) - 1; m &= m - 1;
                int g = w * 32 + j;
                float r = (g == best_g) ? 2.0f : 1.0f;
                float4 gb = s_gb[g];
                float iv = dev_ciou(pb.x, pb.y, pb.z, pb.w, gb.x, gb.y, gb.z, gb.w);
                float s = srow[s_gl[g]];
                float av = (s * powf(iv, 6.0f)) * s_gm[g];
                M = fmaxf(M, av * r);
                mxiou = fmaxf(mxiou, iv * r);
            }
        }
        if (!eff_best) {   // one_hot_best adds weight 1 at best_g
            float4 gb = s_gb[best_g];
            float iv = dev_ciou(pb.x, pb.y, pb.z, pb.w, gb.x, gb.y, gb.z, gb.w);
            M = fmaxf(M, best_v);
            mxiou = fmaxf(mxiou, iv);
        }
    }

    float norm = (M * M) / (mxiou + 1e-9f);
    int cls = s_gl[tgt];
    float4 gb = s_gb[tgt];
    o_cls[t] = (float)cls;
    ((float4*)o_bbox)[t] = gb;
    o_mask[t] = fmask;
    o_norm[t] = norm;
    float* orow = o_scores + t * (size_t)NC;
    #pragma unroll
    for (int j = 0; j < NC / 4; j++) {
        int base = j * 4;
        float4 z;
        z.x = (cls == base + 0) ? norm : 0.0f;
        z.y = (cls == base + 1) ? norm : 0.0f;
        z.z = (cls == base + 2) ? norm : 0.0f;
        z.w = (cls == base + 3) ? norm : 0.0f;
        ((float4*)orow)[j] = z;
    }
}

extern "C" void kernel_launch(void* const* d_in, const int* in_sizes, int n_in,
                              void* d_out, int out_size, void* d_ws, size_t ws_size,
                              hipStream_t stream) {
    const float* pd_scores = (const float*)d_in[0];
    const float* pd_bboxes = (const float*)d_in[1];
    const float* anc       = (const float*)d_in[2];
    const int*   glab      = (const int*)d_in[3];
    const float* gboxes    = (const float*)d_in[4];
    const float* gmask     = (const float*)d_in[5];
    float* out = (float*)d_out;

    char* ws = (char*)d_ws;
    unsigned int*       bits    = (unsigned int*)(ws + OFF_BITS);
    unsigned int*       selcnt  = (unsigned int*)(ws + OFF_SELCNT);
    int*                flag    = (int*)(ws + OFF_FLAG);
    unsigned long long* bestkey = (unsigned long long*)(ws + OFF_BESTK);

    k_init<<<(BS * NA + 255) / 256, 256, 0, stream>>>(bits, selcnt, flag, bestkey);

    k_build_select<<<dim3(BS * NG / 4), 256, 0, stream>>>(
        pd_scores, pd_bboxes, anc, glab, gboxes, gmask, bits, selcnt, flag, bestkey);

    k_final<<<dim3((NA + 255) / 256, BS), 256, 0, stream>>>(
        pd_scores, pd_bboxes, glab, gboxes, gmask, bits, flag, bestkey,
        out + OUT_CLS, out + OUT_BBOX, out + OUT_SCORES, out + OUT_MASK, out + OUT_NORM);
}

// Round 7
// 142.807 us; speedup vs baseline: 1.1127x; 1.1127x over previous
//
#include <hip/hip_runtime.h>
#include <math.h>

#pragma clang fp contract(off)

#define BS 16
#define NA 8400
#define NG 128
#define NC 80
#define KTOP 13
#define CAP 1024   // per-column candidate-list capacity (worst case ~500)

// ---- workspace layout (bytes) ----
#define OFF_COUNTS 0                                    // 2048 u32       = 8192
#define OFF_BITS   (OFF_COUNTS + BS * NG * 4)           // BS*NA*4 u32    = 2,150,400
#define OFF_SELCNT (OFF_BITS + (size_t)BS * NA * 16)    // BS*NA u32      =   537,600
#define OFF_FLAG   (OFF_SELCNT + (size_t)BS * NA * 4)   // 256 bytes
#define ZERO_END   (OFF_FLAG + 256)
#define OFF_PAIRS  ZERO_END                             // 2048*CAP*8     = 16,777,216
#define OFF_BESTK  (OFF_PAIRS + (size_t)BS * NG * CAP * 8)  // BS*NA u64  = 1,075,200

// ---- output layout (float elements) ----
#define OUT_CLS    0
#define OUT_BBOX   (BS * NA)
#define OUT_SCORES (OUT_BBOX + BS * NA * 4)
#define OUT_MASK   (OUT_SCORES + BS * NA * NC)
#define OUT_NORM   (OUT_MASK + BS * NA)

__device__ __forceinline__ float dev_ciou(float px1, float py1, float px2, float py2,
                                          float gx1, float gy1, float gx2, float gy2) {
    const float eps = 1e-7f;
    float iw = fminf(px2, gx2) - fmaxf(px1, gx1); iw = fmaxf(iw, 0.0f);
    float ih = fminf(py2, gy2) - fmaxf(py1, gy1); ih = fmaxf(ih, 0.0f);
    float inter = iw * ih;
    float w1 = px2 - px1;
    float h1 = (py2 - py1) + eps;
    float w2 = gx2 - gx1;
    float h2 = (gy2 - gy1) + eps;
    float uni = ((w1 * h1 + w2 * h2) - inter) + eps;
    float iou = inter / uni;
    float cw = fmaxf(px2, gx2) - fminf(px1, gx1);
    float ch = fmaxf(py2, gy2) - fminf(py1, gy1);
    float c2 = (cw * cw + ch * ch) + eps;
    float tx = ((gx1 + gx2) - px1) - px2;
    float ty = ((gy1 + gy2) - py1) - py2;
    float rho2 = (tx * tx + ty * ty) / 4.0f;
    float da = atanf(w2 / h2) - atanf(w1 / h1);
    float v = ((float)(4.0 / (M_PI * M_PI))) * (da * da);
    float alpha = v / ((v - iou) + (float)(1.0 + 1e-7));
    float res = iou - (rho2 / c2 + v * alpha);
    return fmaxf(res, 0.0f);
}

// K1: compact-then-compute, block = 64 anchors x 4 g-chunk waves (132x16 grid).
// Phase 1: ballot-compacted per-wave LDS queues (no atomics at all).
// Phase 2: dense drain — ciou/powf at ~full lane utilization; per-column global
//          candidate lists; per-anchor argmax via LDS u64 atomicMax.
// Phase 3: plain coalesced store of packed bestkey (block owns its anchors).
__global__ __launch_bounds__(256) void k_build(
    const float* __restrict__ scores, const float* __restrict__ pboxes,
    const float* __restrict__ anc, const int* __restrict__ glab,
    const float* __restrict__ gboxes, const float* __restrict__ gmask,
    unsigned int* __restrict__ counts, uint2* __restrict__ pairs,
    unsigned long long* __restrict__ bestkey)
{
    __shared__ float4 s_gb[NG];
    __shared__ int s_gl[NG];
    __shared__ float s_gm[NG];
    __shared__ unsigned short s_q[4][2048];   // per-wave queues, worst case 64*32
    __shared__ int s_qlen[4];
    __shared__ unsigned long long s_best[64];
    int b = blockIdx.y;
    int tid = threadIdx.x;
    for (int i = tid; i < NG; i += 256) {
        s_gb[i] = ((const float4*)gboxes)[b * NG + i];
        s_gl[i] = glab[b * NG + i];
        s_gm[i] = gmask[b * NG + i];
    }
    if (tid < 64) s_best[tid] = 127ULL;   // pack(al=0.0f, g=0)
    __syncthreads();

    int wv = tid >> 6, lane = tid & 63;
    int a0 = blockIdx.x * 64;
    int a = a0 + lane;
    bool valid = (a < NA);
    float ax = -1e30f, ay = -1e30f;
    if (valid) { float2 ap = ((const float2*)anc)[a]; ax = ap.x; ay = ap.y; }
    unsigned long long lmask = (1ULL << lane) - 1ULL;
    unsigned short* q = s_q[wv];

    // phase 1: ballot-compacted in-box scan, wave-private queue, no atomics
    int qn = 0;
    for (int j = 0; j < 32; j++) {
        int g = wv * 32 + j;
        float4 gb = s_gb[g];
        float mn = fminf(fminf(ax - gb.x, ay - gb.y), fminf(gb.z - ax, gb.w - ay));
        bool hit = valid && (mn > 1e-9f) && (s_gm[g] != 0.0f);
        unsigned long long bal = __ballot(hit);
        if (hit) q[qn + __popcll(bal & lmask)] = (unsigned short)((lane << 7) | g);
        qn += __popcll(bal);
    }
    if (lane == 0) s_qlen[wv] = qn;
    __syncthreads();

    // phase 2: dense drain of all 4 queues
    for (int s = 0; s < 4; s++) {
        int len = s_qlen[s];
        const unsigned short* qq = s_q[s];
        for (int i = tid; i < len; i += 256) {
            int e = (int)qq[i];
            int al_ = e >> 7, g = e & 127;
            int aa = a0 + al_;
            size_t t = (size_t)b * NA + aa;
            float4 gb = s_gb[g];
            float4 pb = ((const float4*)pboxes)[t];
            float iou = dev_ciou(pb.x, pb.y, pb.z, pb.w, gb.x, gb.y, gb.z, gb.w);
            float sc = scores[t * NC + s_gl[g]];
            float al = (sc * powf(iou, 6.0f)) * s_gm[g];   // same expr as reference
            if (al > 1e-9f) {
                int col = b * NG + g;
                unsigned int pos = atomicAdd(&counts[col], 1u);
                if (pos < CAP)
                    pairs[(size_t)col * CAP + pos] =
                        make_uint2(__float_as_uint(al), (unsigned int)aa);
            }
            // first-occurrence argmax: al>=0 -> bits order-monotone; (127-g)
            // low bits make smaller g win ties under max.
            unsigned long long key =
                ((unsigned long long)__float_as_uint(al) << 32) | (unsigned int)(127 - g);
            atomicMax(&s_best[al_], key);
        }
    }
    __syncthreads();

    // phase 3: coalesced bestkey store (no global atomic; block owns anchors)
    if (tid < 64 && a0 + tid < NA)
        bestkey[(size_t)b * NA + a0 + tid] = s_best[tid];
}

// K2: one wave per column, candidate list in REGISTERS (entries pre-filtered
// >1e-9). Top-13 value-desc / anchor-asc = jax.lax.top_k; batched atomics.
__global__ __launch_bounds__(256) void k_select(
    const unsigned int* __restrict__ counts, const uint2* __restrict__ pairs,
    const float* __restrict__ gmask,
    unsigned int* __restrict__ bits, unsigned int* __restrict__ selcnt,
    int* __restrict__ flag)
{
    int wv = threadIdx.x >> 6, lane = threadIdx.x & 63;
    int col = blockIdx.x * 4 + wv;
    if (!(gmask[col] > 0.0f)) return;   // column excluded from is_in
    int b = col >> 7, g = col & 127;
    int cnt = (int)counts[col]; if (cnt > CAP) cnt = CAP;
    int nch = (cnt + 63) >> 6;
    float v[CAP / 64]; unsigned int ai[CAP / 64];
    #pragma unroll
    for (int j = 0; j < CAP / 64; j++) {
        int i = j * 64 + lane;
        if (i < cnt) {
            uint2 p = pairs[(size_t)col * CAP + i];
            v[j] = __uint_as_float(p.x); ai[j] = p.y;
        } else { v[j] = -1.0f; ai[j] = 0xFFFFFFFFu; }
    }
    unsigned int wins[KTOP];
    int nw = 0;
    for (int k = 0; k < KTOP; k++) {
        float bv = -1.0f; unsigned int ba = 0xFFFFFFFFu;
        #pragma unroll
        for (int j = 0; j < CAP / 64; j++) {
            if (j < nch) {
                if (v[j] > bv || (v[j] == bv && ai[j] < ba)) { bv = v[j]; ba = ai[j]; }
            }
        }
        for (int off = 1; off < 64; off <<= 1) {
            float ov = __shfl_xor(bv, off);
            unsigned int oa = (unsigned int)__shfl_xor((int)ba, off);
            if (ov > bv || (ov == bv && oa < ba)) { bv = ov; ba = oa; }
        }
        if (!(bv > 1e-9f)) break;   // list exhausted (entries all >1e-9)
        wins[k] = ba; nw = k + 1;
        #pragma unroll
        for (int j = 0; j < CAP / 64; j++) {
            if (ai[j] == ba) v[j] = -1.0f;   // anchors unique within a column
        }
    }
    if (lane == 0 && nw > 0) {
        unsigned int olds[KTOP];
        #pragma unroll
        for (int k = 0; k < KTOP; k++) {
            if (k < nw) {
                size_t t = (size_t)b * NA + wins[k];
                atomicOr(&bits[t * 4 + (g >> 5)], 1u << (g & 31));   // no return
                olds[k] = atomicAdd(&selcnt[t], 1u);                 // batched waits
            }
        }
        bool c = false;
        #pragma unroll
        for (int k = 0; k < KTOP; k++) {
            if (k < nw && olds[k] >= 1u) c = true;
        }
        if (c) atomicOr(flag, 1);
    }
}

// K3: per-anchor resolution + all 5 outputs (align/iou recomputed only at set bits)
__global__ __launch_bounds__(256) void k_final(
    const float* __restrict__ scores, const float* __restrict__ pboxes,
    const int* __restrict__ glab, const float* __restrict__ gboxes,
    const float* __restrict__ gmask,
    const unsigned int* __restrict__ bits, const int* __restrict__ flagp,
    const unsigned long long* __restrict__ bestkey,
    float* __restrict__ o_cls, float* __restrict__ o_bbox, float* __restrict__ o_scores,
    float* __restrict__ o_mask, float* __restrict__ o_norm)
{
    __shared__ float4 s_gb[NG];
    __shared__ int s_gl[NG];
    __shared__ float s_gm[NG];
    int b = blockIdx.y;
    for (int i = threadIdx.x; i < NG; i += 256) {
        s_gb[i] = ((const float4*)gboxes)[b * NG + i];
        s_gl[i] = glab[b * NG + i];
        s_gm[i] = gmask[b * NG + i];
    }
    __syncthreads();
    int a = blockIdx.x * 256 + threadIdx.x;
    if (a >= NA) return;
    size_t t = (size_t)b * NA + a;
    unsigned int ew[4];
    ew[0] = bits[t * 4 + 0]; ew[1] = bits[t * 4 + 1];
    ew[2] = bits[t * 4 + 2]; ew[3] = bits[t * 4 + 3];
    int cnt = __popc(ew[0]) + __popc(ew[1]) + __popc(ew[2]) + __popc(ew[3]);
    bool conflict_any = (flagp[0] != 0);
    unsigned long long key = bestkey[t];
    float best_v = __uint_as_float((unsigned int)(key >> 32));
    int best_g = 127 - (int)(key & 0x7Fu);
    float4 pb = ((const float4*)pboxes)[t];
    const float* srow = scores + t * NC;

    bool keep = (cnt <= 1);
    float M = 0.0f, mxiou = 0.0f;
    int tgt = 0;
    float fmask = 0.0f;

    if (!conflict_any) {
        fmask = (cnt > 0) ? 1.0f : 0.0f;
        for (int w = 0; w < 4; w++) {
            if (ew[w]) { tgt = w * 32 + __ffs(ew[w]) - 1; break; }
        }
        for (int w = 0; w < 4; w++) {
            unsigned int m = ew[w];
            while (m) {
                int j = __ffs(m) - 1; m &= m - 1;
                int g = w * 32 + j;
                float4 gb = s_gb[g];
                float iv = dev_ciou(pb.x, pb.y, pb.z, pb.w, gb.x, gb.y, gb.z, gb.w);
                float s = srow[s_gl[g]];
                float av = (s * powf(iv, 6.0f)) * s_gm[g];   // bit-identical to build
                M = fmaxf(M, av);
                mxiou = fmaxf(mxiou, iv);
            }
        }
    } else if (!keep) {
        fmask = 0.0f; tgt = 0; M = 0.0f; mxiou = 0.0f;   // resolved row all zero
    } else {
        fmask = 1.0f;   // one_hot_best always contributes
        bool eff_best = ((ew[best_g >> 5] >> (best_g & 31)) & 1u) != 0u;
        int first_eff = 1 << 30;
        for (int w = 0; w < 4; w++) {
            if (ew[w]) { first_eff = w * 32 + __ffs(ew[w]) - 1; break; }
        }
        tgt = eff_best ? best_g : (first_eff < best_g ? first_eff : best_g);
        for (int w = 0; w < 4; w++) {
            unsigned int m = ew[w];
            while (m) {
                int j = __ffs(m) - 1; m &= m - 1;
                int g = w * 32 + j;
                float r = (g == best_g) ? 2.0f : 1.0f;
                float4 gb = s_gb[g];
                float iv = dev_ciou(pb.x, pb.y, pb.z, pb.w, gb.x, gb.y, gb.z, gb.w);
                float s = srow[s_gl[g]];
                float av = (s * powf(iv, 6.0f)) * s_gm[g];
                M = fmaxf(M, av * r);
                mxiou = fmaxf(mxiou, iv * r);
            }
        }
        if (!eff_best) {   // one_hot_best adds weight 1 at best_g
            float4 gb = s_gb[best_g];
            float iv = dev_ciou(pb.x, pb.y, pb.z, pb.w, gb.x, gb.y, gb.z, gb.w);
            M = fmaxf(M, best_v);
            mxiou = fmaxf(mxiou, iv);
        }
    }

    float norm = (M * M) / (mxiou + 1e-9f);
    int cls = s_gl[tgt];
    float4 gb = s_gb[tgt];
    o_cls[t] = (float)cls;
    ((float4*)o_bbox)[t] = gb;
    o_mask[t] = fmask;
    o_norm[t] = norm;
    float* orow = o_scores + t * (size_t)NC;
    #pragma unroll
    for (int j = 0; j < NC / 4; j++) {
        int base = j * 4;
        float4 z;
        z.x = (cls == base + 0) ? norm : 0.0f;
        z.y = (cls == base + 1) ? norm : 0.0f;
        z.z = (cls == base + 2) ? norm : 0.0f;
        z.w = (cls == base + 3) ? norm : 0.0f;
        ((float4*)orow)[j] = z;
    }
}

extern "C" void kernel_launch(void* const* d_in, const int* in_sizes, int n_in,
                              void* d_out, int out_size, void* d_ws, size_t ws_size,
                              hipStream_t stream) {
    const float* pd_scores = (const float*)d_in[0];
    const float* pd_bboxes = (const float*)d_in[1];
    const float* anc       = (const float*)d_in[2];
    const int*   glab      = (const int*)d_in[3];
    const float* gboxes    = (const float*)d_in[4];
    const float* gmask     = (const float*)d_in[5];
    float* out = (float*)d_out;

    char* ws = (char*)d_ws;
    unsigned int*       counts  = (unsigned int*)(ws + OFF_COUNTS);
    unsigned int*       bits    = (unsigned int*)(ws + OFF_BITS);
    unsigned int*       selcnt  = (unsigned int*)(ws + OFF_SELCNT);
    int*                flag    = (int*)(ws + OFF_FLAG);
    uint2*              pairs   = (uint2*)(ws + OFF_PAIRS);
    unsigned long long* bestkey = (unsigned long long*)(ws + OFF_BESTK);

    hipMemsetAsync(ws, 0, ZERO_END, stream);

    k_build<<<dim3((NA + 63) / 64, BS), 256, 0, stream>>>(
        pd_scores, pd_bboxes, anc, glab, gboxes, gmask, counts, pairs, bestkey);

    k_select<<<dim3(BS * NG / 4), 256, 0, stream>>>(
        counts, pairs, gmask, bits, selcnt, flag);

    k_final<<<dim3((NA + 255) / 256, BS), 256, 0, stream>>>(
        pd_scores, pd_bboxes, glab, gboxes, gmask, bits, flag, bestkey,
        out + OUT_CLS, out + OUT_BBOX, out + OUT_SCORES, out + OUT_MASK, out + OUT_NORM);
}

// Round 8
// 135.012 us; speedup vs baseline: 1.1770x; 1.0577x over previous
//
#include <hip/hip_runtime.h>
#include <math.h>

#pragma clang fp contract(off)

#define BS 16
#define NA 8400
#define NG 128
#define NC 80
#define KTOP 13
#define CAP 1024   // per-column candidate-list capacity (worst case ~500)

// ---- workspace layout (bytes) ----
#define OFF_COUNTS 0                                    // 2048 u32       = 8192
#define OFF_BITS   (OFF_COUNTS + BS * NG * 4)           // BS*NA*4 u32    = 2,150,400
#define OFF_SELCNT (OFF_BITS + (size_t)BS * NA * 16)    // BS*NA u32      =   537,600
#define OFF_FLAG   (OFF_SELCNT + (size_t)BS * NA * 4)   // 256 bytes
#define ZERO_END   (OFF_FLAG + 256)
#define OFF_PAIRS  ZERO_END                             // 2048*CAP*8     = 16,777,216
#define OFF_BESTK  (OFF_PAIRS + (size_t)BS * NG * CAP * 8)  // BS*NA u64  = 1,075,200

// ---- output layout (float elements) ----
#define OUT_CLS    0
#define OUT_BBOX   (BS * NA)
#define OUT_SCORES (OUT_BBOX + BS * NA * 4)
#define OUT_MASK   (OUT_SCORES + BS * NA * NC)
#define OUT_NORM   (OUT_MASK + BS * NA)

__device__ __forceinline__ float dev_ciou(float px1, float py1, float px2, float py2,
                                          float gx1, float gy1, float gx2, float gy2) {
    const float eps = 1e-7f;
    float iw = fminf(px2, gx2) - fmaxf(px1, gx1); iw = fmaxf(iw, 0.0f);
    float ih = fminf(py2, gy2) - fmaxf(py1, gy1); ih = fmaxf(ih, 0.0f);
    float inter = iw * ih;
    float w1 = px2 - px1;
    float h1 = (py2 - py1) + eps;
    float w2 = gx2 - gx1;
    float h2 = (gy2 - gy1) + eps;
    float uni = ((w1 * h1 + w2 * h2) - inter) + eps;
    float iou = inter / uni;
    float cw = fmaxf(px2, gx2) - fminf(px1, gx1);
    float ch = fmaxf(py2, gy2) - fminf(py1, gy1);
    float c2 = (cw * cw + ch * ch) + eps;
    float tx = ((gx1 + gx2) - px1) - px2;
    float ty = ((gy1 + gy2) - py1) - py2;
    float rho2 = (tx * tx + ty * ty) / 4.0f;
    float da = atanf(w2 / h2) - atanf(w1 / h1);
    float v = ((float)(4.0 / (M_PI * M_PI))) * (da * da);
    float alpha = v / ((v - iou) + (float)(1.0 + 1e-7));
    float res = iou - (rho2 / c2 + v * alpha);
    return fmaxf(res, 0.0f);
}

// K1: compact-then-compute, block = 64 anchors x 4 g-chunk waves (132x16 grid).
// (unchanged from R7)
__global__ __launch_bounds__(256) void k_build(
    const float* __restrict__ scores, const float* __restrict__ pboxes,
    const float* __restrict__ anc, const int* __restrict__ glab,
    const float* __restrict__ gboxes, const float* __restrict__ gmask,
    unsigned int* __restrict__ counts, uint2* __restrict__ pairs,
    unsigned long long* __restrict__ bestkey)
{
    __shared__ float4 s_gb[NG];
    __shared__ int s_gl[NG];
    __shared__ float s_gm[NG];
    __shared__ unsigned short s_q[4][2048];
    __shared__ int s_qlen[4];
    __shared__ unsigned long long s_best[64];
    int b = blockIdx.y;
    int tid = threadIdx.x;
    for (int i = tid; i < NG; i += 256) {
        s_gb[i] = ((const float4*)gboxes)[b * NG + i];
        s_gl[i] = glab[b * NG + i];
        s_gm[i] = gmask[b * NG + i];
    }
    if (tid < 64) s_best[tid] = 127ULL;   // pack(al=0.0f, g=0)
    __syncthreads();

    int wv = tid >> 6, lane = tid & 63;
    int a0 = blockIdx.x * 64;
    int a = a0 + lane;
    bool valid = (a < NA);
    float ax = -1e30f, ay = -1e30f;
    if (valid) { float2 ap = ((const float2*)anc)[a]; ax = ap.x; ay = ap.y; }
    unsigned long long lmask = (1ULL << lane) - 1ULL;
    unsigned short* q = s_q[wv];

    // phase 1: ballot-compacted in-box scan, wave-private queue, no atomics
    int qn = 0;
    for (int j = 0; j < 32; j++) {
        int g = wv * 32 + j;
        float4 gb = s_gb[g];
        float mn = fminf(fminf(ax - gb.x, ay - gb.y), fminf(gb.z - ax, gb.w - ay));
        bool hit = valid && (mn > 1e-9f) && (s_gm[g] != 0.0f);
        unsigned long long bal = __ballot(hit);
        if (hit) q[qn + __popcll(bal & lmask)] = (unsigned short)((lane << 7) | g);
        qn += __popcll(bal);
    }
    if (lane == 0) s_qlen[wv] = qn;
    __syncthreads();

    // phase 2: dense drain of all 4 queues
    for (int s = 0; s < 4; s++) {
        int len = s_qlen[s];
        const unsigned short* qq = s_q[s];
        for (int i = tid; i < len; i += 256) {
            int e = (int)qq[i];
            int al_ = e >> 7, g = e & 127;
            int aa = a0 + al_;
            size_t t = (size_t)b * NA + aa;
            float4 gb = s_gb[g];
            float4 pb = ((const float4*)pboxes)[t];
            float iou = dev_ciou(pb.x, pb.y, pb.z, pb.w, gb.x, gb.y, gb.z, gb.w);
            float sc = scores[t * NC + s_gl[g]];
            float al = (sc * powf(iou, 6.0f)) * s_gm[g];   // same expr as reference
            if (al > 1e-9f) {
                int col = b * NG + g;
                unsigned int pos = atomicAdd(&counts[col], 1u);
                if (pos < CAP)
                    pairs[(size_t)col * CAP + pos] =
                        make_uint2(__float_as_uint(al), (unsigned int)aa);
            }
            unsigned long long key =
                ((unsigned long long)__float_as_uint(al) << 32) | (unsigned int)(127 - g);
            atomicMax(&s_best[al_], key);
        }
    }
    __syncthreads();

    // phase 3: coalesced bestkey store (no global atomic; block owns anchors)
    if (tid < 64 && a0 + tid < NA)
        bestkey[(size_t)b * NA + a0 + tid] = s_best[tid];
}

// K2: one wave per column, candidate list in registers. (unchanged from R7)
__global__ __launch_bounds__(256) void k_select(
    const unsigned int* __restrict__ counts, const uint2* __restrict__ pairs,
    const float* __restrict__ gmask,
    unsigned int* __restrict__ bits, unsigned int* __restrict__ selcnt,
    int* __restrict__ flag)
{
    int wv = threadIdx.x >> 6, lane = threadIdx.x & 63;
    int col = blockIdx.x * 4 + wv;
    if (!(gmask[col] > 0.0f)) return;
    int b = col >> 7, g = col & 127;
    int cnt = (int)counts[col]; if (cnt > CAP) cnt = CAP;
    int nch = (cnt + 63) >> 6;
    float v[CAP / 64]; unsigned int ai[CAP / 64];
    #pragma unroll
    for (int j = 0; j < CAP / 64; j++) {
        int i = j * 64 + lane;
        if (i < cnt) {
            uint2 p = pairs[(size_t)col * CAP + i];
            v[j] = __uint_as_float(p.x); ai[j] = p.y;
        } else { v[j] = -1.0f; ai[j] = 0xFFFFFFFFu; }
    }
    unsigned int wins[KTOP];
    int nw = 0;
    for (int k = 0; k < KTOP; k++) {
        float bv = -1.0f; unsigned int ba = 0xFFFFFFFFu;
        #pragma unroll
        for (int j = 0; j < CAP / 64; j++) {
            if (j < nch) {
                if (v[j] > bv || (v[j] == bv && ai[j] < ba)) { bv = v[j]; ba = ai[j]; }
            }
        }
        for (int off = 1; off < 64; off <<= 1) {
            float ov = __shfl_xor(bv, off);
            unsigned int oa = (unsigned int)__shfl_xor((int)ba, off);
            if (ov > bv || (ov == bv && oa < ba)) { bv = ov; ba = oa; }
        }
        if (!(bv > 1e-9f)) break;
        wins[k] = ba; nw = k + 1;
        #pragma unroll
        for (int j = 0; j < CAP / 64; j++) {
            if (ai[j] == ba) v[j] = -1.0f;
        }
    }
    if (lane == 0 && nw > 0) {
        unsigned int olds[KTOP];
        #pragma unroll
        for (int k = 0; k < KTOP; k++) {
            if (k < nw) {
                size_t t = (size_t)b * NA + wins[k];
                atomicOr(&bits[t * 4 + (g >> 5)], 1u << (g & 31));
                olds[k] = atomicAdd(&selcnt[t], 1u);
            }
        }
        bool c = false;
        #pragma unroll
        for (int k = 0; k < KTOP; k++) {
            if (k < nw && olds[k] >= 1u) c = true;
        }
        if (c) atomicOr(flag, 1);
    }
}

// K3: per-anchor resolution + all 5 outputs. NEW: o_scores one-hot rows are
// written block-cooperatively (the block's 256 anchors form one contiguous
// 80 KB span) via LDS-staged (cls, norm) — fully coalesced float4 stores
// instead of 320-B-strided per-thread row writes.
__global__ __launch_bounds__(256) void k_final(
    const float* __restrict__ scores, const float* __restrict__ pboxes,
    const int* __restrict__ glab, const float* __restrict__ gboxes,
    const float* __restrict__ gmask,
    const unsigned int* __restrict__ bits, const int* __restrict__ flagp,
    const unsigned long long* __restrict__ bestkey,
    float* __restrict__ o_cls, float* __restrict__ o_bbox, float* __restrict__ o_scores,
    float* __restrict__ o_mask, float* __restrict__ o_norm)
{
    __shared__ float4 s_gb[NG];
    __shared__ int s_gl[NG];
    __shared__ float s_gm[NG];
    __shared__ int s_cls[256];
    __shared__ float s_nrm[256];
    int b = blockIdx.y;
    int tid = threadIdx.x;
    for (int i = tid; i < NG; i += 256) {
        s_gb[i] = ((const float4*)gboxes)[b * NG + i];
        s_gl[i] = glab[b * NG + i];
        s_gm[i] = gmask[b * NG + i];
    }
    __syncthreads();
    int a0 = blockIdx.x * 256;
    int a = a0 + tid;
    bool act = (a < NA);
    int cls = 0; float norm = 0.0f;
    if (act) {
        size_t t = (size_t)b * NA + a;
        unsigned int ew[4];
        ew[0] = bits[t * 4 + 0]; ew[1] = bits[t * 4 + 1];
        ew[2] = bits[t * 4 + 2]; ew[3] = bits[t * 4 + 3];
        int cnt = __popc(ew[0]) + __popc(ew[1]) + __popc(ew[2]) + __popc(ew[3]);
        bool conflict_any = (flagp[0] != 0);
        unsigned long long key = bestkey[t];
        float best_v = __uint_as_float((unsigned int)(key >> 32));
        int best_g = 127 - (int)(key & 0x7Fu);
        float4 pb = ((const float4*)pboxes)[t];
        const float* srow = scores + t * NC;

        bool keep = (cnt <= 1);
        float M = 0.0f, mxiou = 0.0f;
        int tgt = 0;
        float fmask = 0.0f;

        if (!conflict_any) {
            fmask = (cnt > 0) ? 1.0f : 0.0f;
            for (int w = 0; w < 4; w++) {
                if (ew[w]) { tgt = w * 32 + __ffs(ew[w]) - 1; break; }
            }
            for (int w = 0; w < 4; w++) {
                unsigned int m = ew[w];
                while (m) {
                    int j = __ffs(m) - 1; m &= m - 1;
                    int g = w * 32 + j;
                    float4 gb = s_gb[g];
                    float iv = dev_ciou(pb.x, pb.y, pb.z, pb.w, gb.x, gb.y, gb.z, gb.w);
                    float s = srow[s_gl[g]];
                    float av = (s * powf(iv, 6.0f)) * s_gm[g];   // bit-identical to build
                    M = fmaxf(M, av);
                    mxiou = fmaxf(mxiou, iv);
                }
            }
        } else if (!keep) {
            fmask = 0.0f; tgt = 0; M = 0.0f; mxiou = 0.0f;
        } else {
            fmask = 1.0f;
            bool eff_best = ((ew[best_g >> 5] >> (best_g & 31)) & 1u) != 0u;
            int first_eff = 1 << 30;
            for (int w = 0; w < 4; w++) {
                if (ew[w]) { first_eff = w * 32 + __ffs(ew[w]) - 1; break; }
            }
            tgt = eff_best ? best_g : (first_eff < best_g ? first_eff : best_g);
            for (int w = 0; w < 4; w++) {
                unsigned int m = ew[w];
                while (m) {
                    int j = __ffs(m) - 1; m &= m - 1;
                    int g = w * 32 + j;
                    float r = (g == best_g) ? 2.0f : 1.0f;
                    float4 gb = s_gb[g];
                    float iv = dev_ciou(pb.x, pb.y, pb.z, pb.w, gb.x, gb.y, gb.z, gb.w);
                    float s = srow[s_gl[g]];
                    float av = (s * powf(iv, 6.0f)) * s_gm[g];
                    M = fmaxf(M, av * r);
                    mxiou = fmaxf(mxiou, iv * r);
                }
            }
            if (!eff_best) {
                float4 gb = s_gb[best_g];
                float iv = dev_ciou(pb.x, pb.y, pb.z, pb.w, gb.x, gb.y, gb.z, gb.w);
                M = fmaxf(M, best_v);
                mxiou = fmaxf(mxiou, iv);
            }
        }

        norm = (M * M) / (mxiou + 1e-9f);
        cls = s_gl[tgt];
        float4 gb = s_gb[tgt];
        o_cls[t] = (float)cls;
        ((float4*)o_bbox)[t] = gb;
        o_mask[t] = fmask;
        o_norm[t] = norm;
    }
    s_cls[tid] = cls;
    s_nrm[tid] = norm;
    __syncthreads();

    // cooperative coalesced one-hot write: block's region is contiguous
    int nA = NA - a0; if (nA > 256) nA = 256;
    int nf4 = nA * (NC / 4);   // float4 count in this block's o_scores span
    float4* region = (float4*)(o_scores + ((size_t)b * NA + a0) * NC);
    for (int f = tid; f < nf4; f += 256) {
        int al_ = f / (NC / 4);          // local anchor
        int jj = f - al_ * (NC / 4);     // float4 index within row
        int c = s_cls[al_];
        float nv = s_nrm[al_];
        int base = jj * 4;
        float4 z;
        z.x = (c == base + 0) ? nv : 0.0f;
        z.y = (c == base + 1) ? nv : 0.0f;
        z.z = (c == base + 2) ? nv : 0.0f;
        z.w = (c == base + 3) ? nv : 0.0f;
        region[f] = z;
    }
}

extern "C" void kernel_launch(void* const* d_in, const int* in_sizes, int n_in,
                              void* d_out, int out_size, void* d_ws, size_t ws_size,
                              hipStream_t stream) {
    const float* pd_scores = (const float*)d_in[0];
    const float* pd_bboxes = (const float*)d_in[1];
    const float* anc       = (const float*)d_in[2];
    const int*   glab      = (const int*)d_in[3];
    const float* gboxes    = (const float*)d_in[4];
    const float* gmask     = (const float*)d_in[5];
    float* out = (float*)d_out;

    char* ws = (char*)d_ws;
    unsigned int*       counts  = (unsigned int*)(ws + OFF_COUNTS);
    unsigned int*       bits    = (unsigned int*)(ws + OFF_BITS);
    unsigned int*       selcnt  = (unsigned int*)(ws + OFF_SELCNT);
    int*                flag    = (int*)(ws + OFF_FLAG);
    uint2*              pairs   = (uint2*)(ws + OFF_PAIRS);
    unsigned long long* bestkey = (unsigned long long*)(ws + OFF_BESTK);

    hipMemsetAsync(ws, 0, ZERO_END, stream);

    k_build<<<dim3((NA + 63) / 64, BS), 256, 0, stream>>>(
        pd_scores, pd_bboxes, anc, glab, gboxes, gmask, counts, pairs, bestkey);

    k_select<<<dim3(BS * NG / 4), 256, 0, stream>>>(
        counts, pairs, gmask, bits, selcnt, flag);

    k_final<<<dim3((NA + 255) / 256, BS), 256, 0, stream>>>(
        pd_scores, pd_bboxes, glab, gboxes, gmask, bits, flag, bestkey,
        out + OUT_CLS, out + OUT_BBOX, out + OUT_SCORES, out + OUT_MASK, out + OUT_NORM);
}